// Round 15
// baseline (148.779 us; speedup 1.0000x reference)
//
#include <hip/hip_runtime.h>
#include <hip/hip_bf16.h>

typedef unsigned short u16;
typedef unsigned int u32;
typedef __bf16 bf16x8 __attribute__((ext_vector_type(8)));
typedef float f32x4 __attribute__((ext_vector_type(4)));

#define DEV static __device__ __forceinline__

#define M4 1152  // w2-space (1029 used)

DEV u16 f2bf(float f) {
  __bf16 b = (__bf16)f;
  return __builtin_bit_cast(u16, b);
}
DEV float bf2f(u16 x) { return __builtin_bit_cast(float, (u32)x << 16); }

DEV void gload_lds16(const void* g, void* l) {
  __builtin_amdgcn_global_load_lds(
      (const __attribute__((address_space(1))) void*)g,
      (__attribute__((address_space(3))) void*)l, 16, 0, 0);
}

// =====================================================================
// prep: {W2,W4,W5,W8u f32->bf16} + {W38 partials} + {Xe gather}
// =====================================================================
__global__ __launch_bounds__(256) void prep(
    const float* __restrict__ sW2, const float* __restrict__ sW4,
    const float* __restrict__ sW5, const float* __restrict__ sW8u,
    u16* __restrict__ dW2, u16* __restrict__ dW4, u16* __restrict__ dW5,
    u16* __restrict__ dW8u,
    const float* __restrict__ W3, const float* __restrict__ W8d,
    float* __restrict__ P38,
    const float* __restrict__ emb_item, u16* __restrict__ Xe) {
  const int b = blockIdx.x;
  if (b < 13312) {
    long t = (long)b * 256 + threadIdx.x;
    const float* s;
    u16* d;
    long r = t;
    if (r < 262144) { s = sW2; d = dW2; }
    else {
      r -= 262144;
      int w = (int)(r >> 20);
      r &= 1048575;
      s = w == 0 ? sW4 : w == 1 ? sW5 : sW8u;
      d = w == 0 ? dW4 : w == 1 ? dW5 : dW8u;
    }
    float4 v = *(const float4*)(s + r * 4);
    ushort4 o;
    o.x = f2bf(v.x); o.y = f2bf(v.y); o.z = f2bf(v.z); o.w = f2bf(v.w);
    *(ushort4*)(d + r * 4) = o;
  } else if (b < 13568) {
    const int wb = b - 13312;
    const int s = wb >> 4;
    const int hb = wb & 15;
    const int h = hb * 256 + threadIdx.x;
    float acc[7] = {0, 0, 0, 0, 0, 0, 0};
    const int d0 = s * 64;
#pragma unroll 8
    for (int dd = 0; dd < 64; ++dd) {
      const int d = d0 + dd;
      float w8 = W8d[(size_t)d * 4096 + h];
#pragma unroll
      for (int n = 0; n < 7; ++n) acc[n] = fmaf(W3[n * 1024 + d], w8, acc[n]);
    }
    float* dst = P38 + (size_t)s * 7 * 4096;
#pragma unroll
    for (int n = 0; n < 7; ++n) dst[(size_t)n * 4096 + h] = acc[n];
  } else {
    const int r = b - 13568;  // r < 64
    const int d = threadIdx.x * 4;
    const int i0 = r > 6 ? 6 : r;
    float4 v = *(const float4*)(emb_item + (size_t)i0 * 1024 + d);
    ushort4 o;
    o.x = f2bf(v.x); o.y = f2bf(v.y); o.z = f2bf(v.z); o.w = f2bf(v.w);
    *(ushort4*)(Xe + (size_t)r * 1024 + d) = o;
  }
}

// =====================================================================
// Encoder stage GEMMs: M=64, N=1024, K=1024, nsplit=16 (nkt=1/block),
// 128 GEMM blocks each. A comes from global (g1) or is computed inline
// from the previous stage's P partials (g2/g3). Rider blocks carry the
// W38 reduce (g1) and E2f reduce (g2).
// =====================================================================

// MFMA core shared by enc kernels: single K-chunk, A in ldsA (swizzled),
// B in ldsB (swizzled), epilogue -> Pdst[s][grow][tile_n+gcol].
#define ENC_MFMA_EPILOGUE(Pdst)                                              \
  {                                                                          \
    f32x4 acc[4][2] = {};                                                    \
    _Pragma("unroll") for (int kk = 0; kk < 2; ++kk) {                       \
      bf16x8 af[4], bfr[2];                                                  \
      const int k8 = kk * 4 + l4;                                            \
      _Pragma("unroll") for (int mi = 0; mi < 4; ++mi) {                     \
        int r = mi * 16 + lm;                                                \
        af[mi] = *(const bf16x8*)&ldsA[r * 64 + ((k8 ^ (r & 7)) * 8)];       \
      }                                                                      \
      _Pragma("unroll") for (int nj = 0; nj < 2; ++nj) {                     \
        int c = wc + nj * 16 + lm;                                           \
        bfr[nj] = *(const bf16x8*)&ldsB[c * 64 + ((k8 ^ (c & 7)) * 8)];      \
      }                                                                      \
      _Pragma("unroll") for (int mi = 0; mi < 4; ++mi)                       \
          _Pragma("unroll") for (int nj = 0; nj < 2; ++nj)                   \
              acc[mi][nj] = __builtin_amdgcn_mfma_f32_16x16x32_bf16(         \
                  af[mi], bfr[nj], acc[mi][nj], 0, 0, 0);                    \
    }                                                                        \
    float* Pb = (Pdst) + (size_t)s * 65536;                                  \
    _Pragma("unroll") for (int mi = 0; mi < 4; ++mi) {                       \
      _Pragma("unroll") for (int r = 0; r < 4; ++r) {                        \
        const int grow = mi * 16 + l4 * 4 + r;                               \
        _Pragma("unroll") for (int nj = 0; nj < 2; ++nj) {                   \
          const int gcol = tile_n + wc + nj * 16 + lm;                       \
          Pb[(size_t)grow * 1024 + gcol] = acc[mi][nj][r];                   \
        }                                                                    \
      }                                                                      \
    }                                                                        \
  }

#define ENC_STAGE_B()                                                        \
  _Pragma("unroll") for (int j = 0; j < 4; ++j) {                            \
    int L = j * 256 + t;                                                     \
    int row = L >> 3;                                                        \
    int g8 = (L & 7) ^ (row & 7);                                            \
    gload_lds16(W2b + ((size_t)(tile_n + row) * 1024 + kbeg + g8 * 8),       \
                &ldsB[L * 8]);                                               \
  }

// D1: blocks [0,112) = W38 reduce; [112,240) = GEMM (A = Xe from global)
__global__ __launch_bounds__(256) void enc_g1(
    const u16* __restrict__ Xe, const u16* __restrict__ W2b,
    float* __restrict__ P1,
    const float* __restrict__ P38, float* __restrict__ W38) {
  const int t = threadIdx.x;
  if (blockIdx.x < 112) {
    int i = blockIdx.x * 256 + t;  // < 7*4096
    float v = 0.f;
#pragma unroll
    for (int s = 0; s < 16; ++s) v += P38[(size_t)s * 28672 + i];
    W38[i] = v;
    return;
  }
  __shared__ __align__(16) u16 ldsA[64 * 64];
  __shared__ __align__(16) u16 ldsB[128 * 64];
  const int lane = t & 63, wave = t >> 6;
  const int lm = lane & 15, l4 = lane >> 4;
  const int bidg = blockIdx.x - 112;            // [0,128)
  const int wg = (bidg & 7) * 16 + (bidg >> 3); // XCD-contig swizzle
  const int s = wg & 15;
  const int tile_n = (wg >> 4) * 128;
  const int kbeg = s * 64;
  const int wc = wave * 32;
#pragma unroll
  for (int j = 0; j < 2; ++j) {
    int L = j * 256 + t;
    int row = L >> 3;
    int g8 = (L & 7) ^ (row & 7);
    gload_lds16(Xe + ((size_t)row * 1024 + kbeg + g8 * 8), &ldsA[L * 8]);
  }
  ENC_STAGE_B()
  __syncthreads();
  ENC_MFMA_EPILOGUE(P1)
}

// D2: blocks [0,64) = E2f[b] = sum_s P1[s][b]; [64,192) = GEMM
// (A[row] = bf16(sum_s P1[s][min(row,6)]), computed inline)
__global__ __launch_bounds__(256) void enc_g2(
    const float* __restrict__ P1, const u16* __restrict__ W2b,
    float* __restrict__ P2, float* __restrict__ E2f) {
  const int t = threadIdx.x;
  if (blockIdx.x < 64) {
    const int b = blockIdx.x;
    const int c = t * 4;
    const float* p0 = P1 + (size_t)b * 1024 + c;
    f32x4 v = *(const f32x4*)p0;
#pragma unroll
    for (int s = 1; s < 16; ++s) v += *(const f32x4*)(p0 + (size_t)s * 65536);
    *(f32x4*)(E2f + (size_t)b * 1024 + c) = v;
    return;
  }
  __shared__ __align__(16) u16 ldsA[64 * 64];
  __shared__ __align__(16) u16 ldsB[128 * 64];
  const int lane = t & 63, wave = t >> 6;
  const int lm = lane & 15, l4 = lane >> 4;
  const int bidg = blockIdx.x - 64;
  const int wg = (bidg & 7) * 16 + (bidg >> 3);
  const int s = wg & 15;
  const int tile_n = (wg >> 4) * 128;
  const int kbeg = s * 64;
  const int wc = wave * 32;
  // A-prologue: 64x64 tile from P1 sums (clamped rows), swizzled ds_write
#pragma unroll
  for (int e = 0; e < 16; ++e) {
    int idx = e * 256 + t;
    int row = idx >> 6, col = idx & 63;
    int mc = row > 6 ? 6 : row;
    float v = 0.f;
#pragma unroll
    for (int sp = 0; sp < 16; ++sp)
      v += P1[(size_t)sp * 65536 + mc * 1024 + kbeg + col];
    ldsA[row * 64 + ((((col >> 3) ^ (row & 7)) << 3) | (col & 7))] = f2bf(v);
  }
  ENC_STAGE_B()
  __syncthreads();
  ENC_MFMA_EPILOGUE(P2)
}

// D3: 128 GEMM blocks; A[row] = bf16(sum_s P2[s][mc/7] + E2f[mc%7]), mc=min(row,48)
__global__ __launch_bounds__(256) void enc_g3(
    const float* __restrict__ P2, const float* __restrict__ E2f,
    const u16* __restrict__ W2b, float* __restrict__ P3) {
  const int t = threadIdx.x;
  __shared__ __align__(16) u16 ldsA[64 * 64];
  __shared__ __align__(16) u16 ldsB[128 * 64];
  const int lane = t & 63, wave = t >> 6;
  const int lm = lane & 15, l4 = lane >> 4;
  const int bidg = blockIdx.x;
  const int wg = (bidg & 7) * 16 + (bidg >> 3);
  const int s = wg & 15;
  const int tile_n = (wg >> 4) * 128;
  const int kbeg = s * 64;
  const int wc = wave * 32;
#pragma unroll
  for (int e = 0; e < 16; ++e) {
    int idx = e * 256 + t;
    int row = idx >> 6, col = idx & 63;
    u32 mc = row > 48 ? 48u : (u32)row;
    u32 pr = mc / 7u, er = mc % 7u;
    float v = E2f[(size_t)er * 1024 + kbeg + col];
#pragma unroll
    for (int sp = 0; sp < 16; ++sp)
      v += P2[(size_t)sp * 65536 + pr * 1024 + kbeg + col];
    ldsA[row * 64 + ((((col >> 3) ^ (row & 7)) << 3) | (col & 7))] = f2bf(v);
  }
  ENC_STAGE_B()
  __syncthreads();
  ENC_MFMA_EPILOGUE(P3)
}

// =====================================================================
// Split-K 64x128-tile bf16 MFMA GEMM (dbuf, counted vmcnt) -> P[s][m][n]
// =====================================================================
__global__ __launch_bounds__(256) void gemm_sk(
    const u16* __restrict__ A, int lda,
    const u16* __restrict__ W, int ldw,
    int kchunk, int nbn, int nsplit,
    float* __restrict__ P, int mstride) {
  __shared__ __align__(16) u16 ldsA[2][64 * 64];
  __shared__ __align__(16) u16 ldsB[2][128 * 64];

  const int t = threadIdx.x;
  const int lane = t & 63;
  const int wave = t >> 6;
  const int lm = lane & 15;
  const int l4 = lane >> 4;

  const int nwg = gridDim.x;
  const int bid = blockIdx.x;
  const int cpx = nwg >> 3;
  const int wg = (bid & 7) * cpx + (bid >> 3);
  const int s = wg % nsplit;
  const int tile = wg / nsplit;
  const int bm = tile / nbn, bn = tile % nbn;
  const int N = nbn << 7;
  const int tile_m = bm * 64, tile_n = bn * 128;

  const int wc = wave * 32;

  f32x4 acc[4][2] = {};

  const int kbeg = s * kchunk;
  const int nkt = kchunk >> 6;

  auto stage = [&](int kt, int buf) {
    const int k0 = kbeg + (kt << 6);
#pragma unroll
    for (int j = 0; j < 2; ++j) {
      int L = j * 256 + t;
      int row = L >> 3;
      int g8 = (L & 7) ^ (row & 7);
      gload_lds16(A + ((size_t)(tile_m + row) * lda + k0 + g8 * 8),
                  &ldsA[buf][L * 8]);
    }
#pragma unroll
    for (int j = 0; j < 4; ++j) {
      int L = j * 256 + t;
      int row = L >> 3;
      int g8 = (L & 7) ^ (row & 7);
      gload_lds16(W + ((size_t)(tile_n + row) * ldw + k0 + g8 * 8),
                  &ldsB[buf][L * 8]);
    }
  };

  stage(0, 0);
  int cur = 0;
  for (int kt = 0; kt < nkt; ++kt) {
    if (kt + 1 < nkt) {
      stage(kt + 1, cur ^ 1);
      asm volatile("s_waitcnt vmcnt(6)" ::: "memory");
    } else {
      asm volatile("s_waitcnt vmcnt(0)" ::: "memory");
    }
    __builtin_amdgcn_s_barrier();

    const u16* lA = ldsA[cur];
    const u16* lB = ldsB[cur];
#pragma unroll
    for (int kk = 0; kk < 2; ++kk) {
      bf16x8 af[4], bfr[2];
      const int k8 = kk * 4 + l4;
#pragma unroll
      for (int mi = 0; mi < 4; ++mi) {
        int r = mi * 16 + lm;
        af[mi] = *(const bf16x8*)&lA[r * 64 + ((k8 ^ (r & 7)) * 8)];
      }
#pragma unroll
      for (int nj = 0; nj < 2; ++nj) {
        int c = wc + nj * 16 + lm;
        bfr[nj] = *(const bf16x8*)&lB[c * 64 + ((k8 ^ (c & 7)) * 8)];
      }
#pragma unroll
      for (int mi = 0; mi < 4; ++mi)
#pragma unroll
        for (int nj = 0; nj < 2; ++nj)
          acc[mi][nj] = __builtin_amdgcn_mfma_f32_16x16x32_bf16(
              af[mi], bfr[nj], acc[mi][nj], 0, 0, 0);
    }
    __builtin_amdgcn_s_barrier();
    cur ^= 1;
  }

  float* Pb = P + (size_t)s * mstride;
#pragma unroll
  for (int mi = 0; mi < 4; ++mi) {
#pragma unroll
    for (int r = 0; r < 4; ++r) {
      const int grow = tile_m + mi * 16 + l4 * 4 + r;
#pragma unroll
      for (int nj = 0; nj < 2; ++nj) {
        const int gcol = tile_n + wc + nj * 16 + lm;
        Pb[(size_t)grow * N + gcol] = acc[mi][nj][r];
      }
    }
  }
}

// ---- expand: out[m] = bf16( Psum[mc/7] + E2f[mc%7] ); special rows = xsrc ----
__global__ __launch_bounds__(256) void r_expand(
    const float* __restrict__ P, int S, int mstride, int mlast,
    const float* __restrict__ E2f, const float* __restrict__ xsrc,
    u16* __restrict__ out) {
  const int m = blockIdx.x;
  const int c = threadIdx.x * 4;
  ushort4 o;
  if (xsrc && m >= 344 && m < 347) {
    float4 v = *(const float4*)(xsrc + (size_t)(m - 344) * 1024 + c);
    o.x = f2bf(v.x); o.y = f2bf(v.y); o.z = f2bf(v.z); o.w = f2bf(v.w);
  } else {
    const int mc = m > mlast ? mlast : m;
    const float* p0 = P + (size_t)((u32)mc / 7u) * 1024 + c;
    f32x4 v = *(const f32x4*)p0;
    for (int s = 1; s < S; ++s) v += *(const f32x4*)(p0 + (size_t)s * mstride);
    v += *(const f32x4*)(E2f + (size_t)((u32)mc % 7u) * 1024 + c);
    o.x = f2bf(v.x); o.y = f2bf(v.y); o.z = f2bf(v.z); o.w = f2bf(v.w);
  }
  *(ushort4*)(out + (size_t)m * 1024 + c) = o;
}

// ---- H1[3v+p][h] = relu( Psum[v][h] + Psum[344+p][h] + b4[h] ), grid 384x4 ----
__global__ __launch_bounds__(256) void rh1(
    const float* __restrict__ P, int S, int mstride,
    const float* __restrict__ b4, u16* __restrict__ H1) {
  const int v = blockIdx.x >> 2;
  const int hb = blockIdx.x & 3;
  const int h = hb * 1024 + threadIdx.x * 4;
  const int vc = v > 342 ? 342 : v;
  const float* p0 = P + (size_t)vc * 4096 + h;
  f32x4 base = *(const f32x4*)p0;
  f32x4 ea[3];
#pragma unroll
  for (int p = 0; p < 3; ++p)
    ea[p] = *(const f32x4*)(P + (size_t)(344 + p) * 4096 + h);
  for (int s = 1; s < S; ++s) {
    const float* ps = P + (size_t)s * mstride;
    base += *(const f32x4*)(ps + (size_t)vc * 4096 + h);
#pragma unroll
    for (int p = 0; p < 3; ++p)
      ea[p] += *(const f32x4*)(ps + (size_t)(344 + p) * 4096 + h);
  }
  base += *(const f32x4*)(b4 + h);
#pragma unroll
  for (int p = 0; p < 3; ++p) {
    f32x4 vv = base + ea[p];
    vv.x = fmaxf(vv.x, 0.f); vv.y = fmaxf(vv.y, 0.f);
    vv.z = fmaxf(vv.z, 0.f); vv.w = fmaxf(vv.w, 0.f);
    ushort4 o;
    o.x = f2bf(vv.x); o.y = f2bf(vv.y); o.z = f2bf(vv.z); o.w = f2bf(vv.w);
    *(ushort4*)(H1 + (size_t)(v * 3 + p) * 4096 + h) = o;
  }
}

// ---- Y1[m] = bf16( Psum5[m] + state3[m/3] + embA[m%3] ), grid 1152 ----
__global__ __launch_bounds__(256) void ry1(
    const float* __restrict__ P, int S, int mstride,
    const u16* __restrict__ X3s, const float* __restrict__ embA,
    u16* __restrict__ Y1) {
  const int m = blockIdx.x;
  const int c = threadIdx.x * 4;
  const float* p0 = P + (size_t)m * 1024 + c;
  f32x4 v = *(const f32x4*)p0;
  for (int s = 1; s < S; ++s) v += *(const f32x4*)(p0 + (size_t)s * mstride);
  ushort4 rv = *(const ushort4*)(X3s + (size_t)((u32)m / 3u) * 1024 + c);
  v.x += bf2f(rv.x); v.y += bf2f(rv.y); v.z += bf2f(rv.z); v.w += bf2f(rv.w);
  v += *(const f32x4*)(embA + (size_t)((u32)m % 3u) * 1024 + c);
  ushort4 o;
  o.x = f2bf(v.x); o.y = f2bf(v.y); o.z = f2bf(v.z); o.w = f2bf(v.w);
  *(ushort4*)(Y1 + (size_t)m * 1024 + c) = o;
}

// =====================================================================
// logits per w2 (3 permute variants + residual), single-split P
// =====================================================================
__global__ __launch_bounds__(256) void logits_w2(
    const float* __restrict__ P,
    const float* __restrict__ b8u, const float* __restrict__ emb_perm,
    const float* __restrict__ W38,
    const u16* __restrict__ Y1, const float* __restrict__ b8d,
    const float* __restrict__ W3, float* __restrict__ logits) {
  const int w2 = blockIdx.x;
  if (w2 >= 1029) return;
  __shared__ float red[4][28];
  const int tid = threadIdx.x;
  const int lane = tid & 63, wave = tid >> 6;

  float ah[3][7] = {};
  float ay[7] = {};

#pragma unroll
  for (int j = 0; j < 4; ++j) {
    const int c = tid * 4 + j * 1024;
    f32x4 s = *(const f32x4*)(P + (size_t)w2 * 4096 + c);
    s += *(const f32x4*)(b8u + c);
#pragma unroll
    for (int p = 0; p < 3; ++p) {
      f32x4 v = s + *(const f32x4*)(emb_perm + (size_t)p * 4096 + c);
      v.x = fmaxf(v.x, 0.f); v.y = fmaxf(v.y, 0.f);
      v.z = fmaxf(v.z, 0.f); v.w = fmaxf(v.w, 0.f);
#pragma unroll
      for (int n = 0; n < 7; ++n) {
        f32x4 w = *(const f32x4*)(W38 + (size_t)n * 4096 + c);
        ah[p][n] += v.x * w.x + v.y * w.y + v.z * w.z + v.w * w.w;
      }
    }
  }
  {
    const int c = tid * 4;
    ushort4 yv = *(const ushort4*)(Y1 + (size_t)w2 * 1024 + c);
    float4 bv = *(const float4*)(b8d + c);
    float y0 = bf2f(yv.x) + bv.x, y1 = bf2f(yv.y) + bv.y;
    float y2 = bf2f(yv.z) + bv.z, y3 = bf2f(yv.w) + bv.w;
#pragma unroll
    for (int n = 0; n < 7; ++n) {
      f32x4 w = *(const f32x4*)(W3 + (size_t)n * 1024 + c);
      ay[n] += y0 * w.x + y1 * w.y + y2 * w.z + y3 * w.w;
    }
  }

#pragma unroll
  for (int p = 0; p < 3; ++p)
#pragma unroll
    for (int n = 0; n < 7; ++n)
#pragma unroll
      for (int off = 32; off > 0; off >>= 1)
        ah[p][n] += __shfl_down(ah[p][n], off);
#pragma unroll
  for (int n = 0; n < 7; ++n)
#pragma unroll
    for (int off = 32; off > 0; off >>= 1)
      ay[n] += __shfl_down(ay[n], off);

  if (lane == 0) {
#pragma unroll
    for (int p = 0; p < 3; ++p)
#pragma unroll
      for (int n = 0; n < 7; ++n) red[wave][p * 7 + n] = ah[p][n];
#pragma unroll
    for (int n = 0; n < 7; ++n) red[wave][21 + n] = ay[n];
  }
  __syncthreads();
  if (tid < 21) {
    const int p = tid / 7, n = tid % 7;
    float v = 0.f;
#pragma unroll
    for (int w = 0; w < 4; ++w) v += red[w][tid] + red[w][21 + n];
    logits[(size_t)(w2 * 3 + p) * 7 + n] = v;
  }
}

// ---- out[idx] = logits[cid(idx/7)*7 + idx%7], coalesced stores ----
__global__ __launch_bounds__(256) void scatter_out(
    const int* __restrict__ items, const int* __restrict__ attr,
    const int* __restrict__ perm, const float* __restrict__ logits,
    float* __restrict__ out) {
  int idx = blockIdx.x * 256 + threadIdx.x;  // < 16384*7
  u32 m = (u32)idx / 7u;
  u32 n = (u32)idx - m * 7u;
  int cid = ((items[m * 3] * 7 + items[m * 3 + 1]) * 7 + items[m * 3 + 2]) * 9 +
            attr[m] * 3 + perm[m];
  out[idx] = logits[(size_t)cid * 7 + n];
}

extern "C" void kernel_launch(void* const* d_in, const int* in_sizes, int n_in,
                              void* d_out, int out_size, void* d_ws, size_t ws_size,
                              hipStream_t stream) {
  const int* items = (const int*)d_in[0];
  const int* attr = (const int*)d_in[1];
  const int* perm = (const int*)d_in[2];
  const float* emb_item = (const float*)d_in[3];
  const float* W2 = (const float*)d_in[4];
  const float* W3 = (const float*)d_in[5];
  const float* emb_attr = (const float*)d_in[6];
  const float* W4 = (const float*)d_in[7];
  const float* b4 = (const float*)d_in[8];
  const float* W5 = (const float*)d_in[9];
  const float* W8u = (const float*)d_in[10];
  const float* b8u = (const float*)d_in[11];
  const float* W8d = (const float*)d_in[12];
  const float* b8d = (const float*)d_in[13];
  const float* emb_perm = (const float*)d_in[14];

  const int B = 16384, DIM = 1024, HID = 4096;

  char* ws = (char*)d_ws;
  size_t off = 0;
  auto alloc = [&](size_t bytes) {
    void* p = ws + off;
    off += (bytes + 255) & ~255ull;
    return p;
  };
  u16* W2b = (u16*)alloc((size_t)DIM * DIM * 2);
  u16* W4b = (u16*)alloc((size_t)HID * DIM * 2);
  u16* W5b = (u16*)alloc((size_t)DIM * HID * 2);
  u16* W8ub = (u16*)alloc((size_t)HID * DIM * 2);
  u16* Xe = (u16*)alloc((size_t)64 * DIM * 2);
  float* E2f = (float*)alloc((size_t)64 * DIM * 4);
  u16* X3s = (u16*)alloc((size_t)384 * DIM * 2);  // 0..342 state3; 344..346 embA
  u16* H1 = (u16*)alloc((size_t)M4 * HID * 2);
  u16* Y1 = (u16*)alloc((size_t)M4 * DIM * 2);
  float* P38 = (float*)alloc((size_t)16 * 7 * HID * 4);
  float* W38 = (float*)alloc((size_t)7 * HID * 4);
  float* logits = (float*)alloc((size_t)3087 * 7 * 4);

  float* P = (float*)(ws + off);
  float* P1 = P;                       // 16 x 64 x 1024 f32 = 4.19 MB
  float* P2 = P + 1048576;             // disjoint (intra-dispatch read/write)
  float* P3 = P + 2097152;
  const int S4 = 2;  // FFN1-up: P = 12.6 MB (reuses P base; prior consumers done)
  const int S5 = 4;  // FFN1-down: P = 18.9 MB
  const int S6 = 1;  // FFN2-up: P = 18.9 MB

  // prep: cvt + W38 partials + Xe
  prep<<<13632, 256, 0, stream>>>(W2, W4, W5, W8u, W2b, W4b, W5b, W8ub,
                                  W3, W8d, P38, emb_item, Xe);

  // ---- encoder: 3 dispatches (reduce work folded as riders/prologues) ----
  enc_g1<<<240, 256, 0, stream>>>(Xe, W2b, P1, P38, W38);
  enc_g2<<<192, 256, 0, stream>>>(P1, W2b, P2, E2f);
  enc_g3<<<128, 256, 0, stream>>>(P2, E2f, W2b, P3);
  // X3s[m] = bf16(P3sum[mc/7] + E2f[mc%7]); rows 344-346 = embA
  r_expand<<<384, 256, 0, stream>>>(P3, 16, 64 * DIM, 342, E2f, emb_attr, X3s);

  // ---- FFN1-up at 384 rows (stacked embA); H1 trio-expanded ----
  gemm_sk<<<6 * 32 * S4, 256, 0, stream>>>(X3s, DIM, W4b, DIM, DIM / S4, 32, S4,
                                           P, 384 * HID);
  rh1<<<1536, 256, 0, stream>>>(P, S4, 384 * HID, b4, H1);

  // ---- FFN1-down (K=4096) ----
  gemm_sk<<<18 * 8 * S5, 256, 0, stream>>>(H1, HID, W5b, HID, HID / S5, 8, S5,
                                           P, M4 * DIM);
  ry1<<<M4, 256, 0, stream>>>(P, S5, M4 * DIM, X3s, emb_attr, Y1);

  // ---- FFN2-up (no split); down-proj folded into W38 tail ----
  gemm_sk<<<18 * 32, 256, 0, stream>>>(Y1, DIM, W8ub, DIM, DIM / S6, 32, S6,
                                       P, M4 * HID);
  logits_w2<<<M4, 256, 0, stream>>>(P, b8u, emb_perm, W38, Y1, b8d, W3, logits);

  // out[b] = logits[cid(b)]
  scatter_out<<<B * 7 / 256, 256, 0, stream>>>(items, attr, perm, logits,
                                               (float*)d_out);
}

// Round 16
// 131.236 us; speedup vs baseline: 1.1337x; 1.1337x over previous
//
#include <hip/hip_runtime.h>
#include <hip/hip_bf16.h>

typedef unsigned short u16;
typedef unsigned int u32;
typedef __bf16 bf16x8 __attribute__((ext_vector_type(8)));
typedef float f32x4 __attribute__((ext_vector_type(4)));

#define DEV static __device__ __forceinline__

#define M4 1152  // w2-space (1029 used)

DEV u16 f2bf(float f) {
  __bf16 b = (__bf16)f;
  return __builtin_bit_cast(u16, b);
}
DEV float bf2f(u16 x) { return __builtin_bit_cast(float, (u32)x << 16); }

DEV void gload_lds16(const void* g, void* l) {
  __builtin_amdgcn_global_load_lds(
      (const __attribute__((address_space(1))) void*)g,
      (__attribute__((address_space(3))) void*)l, 16, 0, 0);
}

// =====================================================================
// prep: {W2,W4,W5,W8u f32->bf16} + {W38 partials} + {Xe gather}
// =====================================================================
__global__ __launch_bounds__(256) void prep(
    const float* __restrict__ sW2, const float* __restrict__ sW4,
    const float* __restrict__ sW5, const float* __restrict__ sW8u,
    u16* __restrict__ dW2, u16* __restrict__ dW4, u16* __restrict__ dW5,
    u16* __restrict__ dW8u,
    const float* __restrict__ W3, const float* __restrict__ W8d,
    float* __restrict__ P38,
    const float* __restrict__ emb_item, u16* __restrict__ Xe) {
  const int b = blockIdx.x;
  if (b < 13312) {
    long t = (long)b * 256 + threadIdx.x;
    const float* s;
    u16* d;
    long r = t;
    if (r < 262144) { s = sW2; d = dW2; }
    else {
      r -= 262144;
      int w = (int)(r >> 20);
      r &= 1048575;
      s = w == 0 ? sW4 : w == 1 ? sW5 : sW8u;
      d = w == 0 ? dW4 : w == 1 ? dW5 : dW8u;
    }
    float4 v = *(const float4*)(s + r * 4);
    ushort4 o;
    o.x = f2bf(v.x); o.y = f2bf(v.y); o.z = f2bf(v.z); o.w = f2bf(v.w);
    *(ushort4*)(d + r * 4) = o;
  } else if (b < 13568) {
    const int wb = b - 13312;
    const int s = wb >> 4;
    const int hb = wb & 15;
    const int h = hb * 256 + threadIdx.x;
    float acc[7] = {0, 0, 0, 0, 0, 0, 0};
    const int d0 = s * 64;
#pragma unroll 8
    for (int dd = 0; dd < 64; ++dd) {
      const int d = d0 + dd;
      float w8 = W8d[(size_t)d * 4096 + h];
#pragma unroll
      for (int n = 0; n < 7; ++n) acc[n] = fmaf(W3[n * 1024 + d], w8, acc[n]);
    }
    float* dst = P38 + (size_t)s * 7 * 4096;
#pragma unroll
    for (int n = 0; n < 7; ++n) dst[(size_t)n * 4096 + h] = acc[n];
  } else {
    const int r = b - 13568;  // r < 64
    const int d = threadIdx.x * 4;
    const int i0 = r > 6 ? 6 : r;
    float4 v = *(const float4*)(emb_item + (size_t)i0 * 1024 + d);
    ushort4 o;
    o.x = f2bf(v.x); o.y = f2bf(v.y); o.z = f2bf(v.z); o.w = f2bf(v.w);
    *(ushort4*)(Xe + (size_t)r * 1024 + d) = o;
  }
}

// =====================================================================
// Split-K 64x128-tile bf16 MFMA GEMM (dbuf, counted vmcnt) -> P[s][m][n]
// =====================================================================
__global__ __launch_bounds__(256) void gemm_sk(
    const u16* __restrict__ A, int lda,
    const u16* __restrict__ W, int ldw,
    int kchunk, int nbn, int nsplit,
    float* __restrict__ P, int mstride) {
  __shared__ __align__(16) u16 ldsA[2][64 * 64];
  __shared__ __align__(16) u16 ldsB[2][128 * 64];

  const int t = threadIdx.x;
  const int lane = t & 63;
  const int wave = t >> 6;
  const int lm = lane & 15;
  const int l4 = lane >> 4;

  const int nwg = gridDim.x;
  const int bid = blockIdx.x;
  const int cpx = nwg >> 3;
  const int wg = (bid & 7) * cpx + (bid >> 3);
  const int s = wg % nsplit;
  const int tile = wg / nsplit;
  const int bm = tile / nbn, bn = tile % nbn;
  const int N = nbn << 7;
  const int tile_m = bm * 64, tile_n = bn * 128;

  const int wc = wave * 32;

  f32x4 acc[4][2] = {};

  const int kbeg = s * kchunk;
  const int nkt = kchunk >> 6;

  auto stage = [&](int kt, int buf) {
    const int k0 = kbeg + (kt << 6);
#pragma unroll
    for (int j = 0; j < 2; ++j) {
      int L = j * 256 + t;
      int row = L >> 3;
      int g8 = (L & 7) ^ (row & 7);
      gload_lds16(A + ((size_t)(tile_m + row) * lda + k0 + g8 * 8),
                  &ldsA[buf][L * 8]);
    }
#pragma unroll
    for (int j = 0; j < 4; ++j) {
      int L = j * 256 + t;
      int row = L >> 3;
      int g8 = (L & 7) ^ (row & 7);
      gload_lds16(W + ((size_t)(tile_n + row) * ldw + k0 + g8 * 8),
                  &ldsB[buf][L * 8]);
    }
  };

  stage(0, 0);
  int cur = 0;
  for (int kt = 0; kt < nkt; ++kt) {
    if (kt + 1 < nkt) {
      stage(kt + 1, cur ^ 1);
      asm volatile("s_waitcnt vmcnt(6)" ::: "memory");
    } else {
      asm volatile("s_waitcnt vmcnt(0)" ::: "memory");
    }
    __builtin_amdgcn_s_barrier();

    const u16* lA = ldsA[cur];
    const u16* lB = ldsB[cur];
#pragma unroll
    for (int kk = 0; kk < 2; ++kk) {
      bf16x8 af[4], bfr[2];
      const int k8 = kk * 4 + l4;
#pragma unroll
      for (int mi = 0; mi < 4; ++mi) {
        int r = mi * 16 + lm;
        af[mi] = *(const bf16x8*)&lA[r * 64 + ((k8 ^ (r & 7)) * 8)];
      }
#pragma unroll
      for (int nj = 0; nj < 2; ++nj) {
        int c = wc + nj * 16 + lm;
        bfr[nj] = *(const bf16x8*)&lB[c * 64 + ((k8 ^ (c & 7)) * 8)];
      }
#pragma unroll
      for (int mi = 0; mi < 4; ++mi)
#pragma unroll
        for (int nj = 0; nj < 2; ++nj)
          acc[mi][nj] = __builtin_amdgcn_mfma_f32_16x16x32_bf16(
              af[mi], bfr[nj], acc[mi][nj], 0, 0, 0);
    }
    __builtin_amdgcn_s_barrier();
    cur ^= 1;
  }

  float* Pb = P + (size_t)s * mstride;
#pragma unroll
  for (int mi = 0; mi < 4; ++mi) {
#pragma unroll
    for (int r = 0; r < 4; ++r) {
      const int grow = tile_m + mi * 16 + l4 * 4 + r;
#pragma unroll
      for (int nj = 0; nj < 2; ++nj) {
        const int gcol = tile_n + wc + nj * 16 + lm;
        Pb[(size_t)grow * N + gcol] = acc[mi][nj][r];
      }
    }
  }
}

// ---- R1 + W38 reduce: blocks [0,64): state1 (bf16+f32); [64,176): W38 ----
__global__ __launch_bounds__(256) void r1w38(
    const float* __restrict__ P, int S, int mstride,
    u16* __restrict__ state1b, float* __restrict__ E2f,
    const float* __restrict__ P38, float* __restrict__ W38) {
  const int b = blockIdx.x;
  if (b < 64) {
    const int c = threadIdx.x * 4;
    const float* p0 = P + (size_t)b * 1024 + c;
    f32x4 v = *(const f32x4*)p0;
    for (int s = 1; s < S; ++s) v += *(const f32x4*)(p0 + (size_t)s * mstride);
    *(f32x4*)(E2f + (size_t)b * 1024 + c) = v;
    ushort4 o;
    o.x = f2bf(v.x); o.y = f2bf(v.y); o.z = f2bf(v.z); o.w = f2bf(v.w);
    *(ushort4*)(state1b + (size_t)b * 1024 + c) = o;
  } else {
    int i = (b - 64) * 256 + threadIdx.x;  // < 7*4096
    float v = 0.f;
#pragma unroll
    for (int s = 0; s < 16; ++s) v += P38[(size_t)s * 28672 + i];
    W38[i] = v;
  }
}

// ---- expand: out[m] = bf16( Psum[mc/7] + E2f[mc%7] ); special rows = xsrc ----
__global__ __launch_bounds__(256) void r_expand(
    const float* __restrict__ P, int S, int mstride, int mlast,
    const float* __restrict__ E2f, const float* __restrict__ xsrc,
    u16* __restrict__ out) {
  const int m = blockIdx.x;
  const int c = threadIdx.x * 4;
  ushort4 o;
  if (xsrc && m >= 344 && m < 347) {
    float4 v = *(const float4*)(xsrc + (size_t)(m - 344) * 1024 + c);
    o.x = f2bf(v.x); o.y = f2bf(v.y); o.z = f2bf(v.z); o.w = f2bf(v.w);
  } else {
    const int mc = m > mlast ? mlast : m;
    const float* p0 = P + (size_t)((u32)mc / 7u) * 1024 + c;
    f32x4 v = *(const f32x4*)p0;
    for (int s = 1; s < S; ++s) v += *(const f32x4*)(p0 + (size_t)s * mstride);
    v += *(const f32x4*)(E2f + (size_t)((u32)mc % 7u) * 1024 + c);
    o.x = f2bf(v.x); o.y = f2bf(v.y); o.z = f2bf(v.z); o.w = f2bf(v.w);
  }
  *(ushort4*)(out + (size_t)m * 1024 + c) = o;
}

// ---- H1[3v+p][h] = relu( Psum[v][h] + Psum[344+p][h] + b4[h] ), grid 384x4 ----
__global__ __launch_bounds__(256) void rh1(
    const float* __restrict__ P, int S, int mstride,
    const float* __restrict__ b4, u16* __restrict__ H1) {
  const int v = blockIdx.x >> 2;
  const int hb = blockIdx.x & 3;
  const int h = hb * 1024 + threadIdx.x * 4;
  const int vc = v > 342 ? 342 : v;
  const float* p0 = P + (size_t)vc * 4096 + h;
  f32x4 base = *(const f32x4*)p0;
  f32x4 ea[3];
#pragma unroll
  for (int p = 0; p < 3; ++p)
    ea[p] = *(const f32x4*)(P + (size_t)(344 + p) * 4096 + h);
  for (int s = 1; s < S; ++s) {
    const float* ps = P + (size_t)s * mstride;
    base += *(const f32x4*)(ps + (size_t)vc * 4096 + h);
#pragma unroll
    for (int p = 0; p < 3; ++p)
      ea[p] += *(const f32x4*)(ps + (size_t)(344 + p) * 4096 + h);
  }
  base += *(const f32x4*)(b4 + h);
#pragma unroll
  for (int p = 0; p < 3; ++p) {
    f32x4 vv = base + ea[p];
    vv.x = fmaxf(vv.x, 0.f); vv.y = fmaxf(vv.y, 0.f);
    vv.z = fmaxf(vv.z, 0.f); vv.w = fmaxf(vv.w, 0.f);
    ushort4 o;
    o.x = f2bf(vv.x); o.y = f2bf(vv.y); o.z = f2bf(vv.z); o.w = f2bf(vv.w);
    *(ushort4*)(H1 + (size_t)(v * 3 + p) * 4096 + h) = o;
  }
}

// ---- Y1[m] = bf16( Psum5[m] + state3[m/3] + embA[m%3] ), grid 1152 ----
__global__ __launch_bounds__(256) void ry1(
    const float* __restrict__ P, int S, int mstride,
    const u16* __restrict__ X3s, const float* __restrict__ embA,
    u16* __restrict__ Y1) {
  const int m = blockIdx.x;
  const int c = threadIdx.x * 4;
  const float* p0 = P + (size_t)m * 1024 + c;
  f32x4 v = *(const f32x4*)p0;
  for (int s = 1; s < S; ++s) v += *(const f32x4*)(p0 + (size_t)s * mstride);
  ushort4 rv = *(const ushort4*)(X3s + (size_t)((u32)m / 3u) * 1024 + c);
  v.x += bf2f(rv.x); v.y += bf2f(rv.y); v.z += bf2f(rv.z); v.w += bf2f(rv.w);
  v += *(const f32x4*)(embA + (size_t)((u32)m % 3u) * 1024 + c);
  ushort4 o;
  o.x = f2bf(v.x); o.y = f2bf(v.y); o.z = f2bf(v.z); o.w = f2bf(v.w);
  *(ushort4*)(Y1 + (size_t)m * 1024 + c) = o;
}

// =====================================================================
// logits per w2 (3 permute variants + residual), single-split P
// =====================================================================
__global__ __launch_bounds__(256) void logits_w2(
    const float* __restrict__ P,
    const float* __restrict__ b8u, const float* __restrict__ emb_perm,
    const float* __restrict__ W38,
    const u16* __restrict__ Y1, const float* __restrict__ b8d,
    const float* __restrict__ W3, float* __restrict__ logits) {
  const int w2 = blockIdx.x;
  if (w2 >= 1029) return;
  __shared__ float red[4][28];
  const int tid = threadIdx.x;
  const int lane = tid & 63, wave = tid >> 6;

  float ah[3][7] = {};
  float ay[7] = {};

#pragma unroll
  for (int j = 0; j < 4; ++j) {
    const int c = tid * 4 + j * 1024;
    f32x4 s = *(const f32x4*)(P + (size_t)w2 * 4096 + c);
    s += *(const f32x4*)(b8u + c);
#pragma unroll
    for (int p = 0; p < 3; ++p) {
      f32x4 v = s + *(const f32x4*)(emb_perm + (size_t)p * 4096 + c);
      v.x = fmaxf(v.x, 0.f); v.y = fmaxf(v.y, 0.f);
      v.z = fmaxf(v.z, 0.f); v.w = fmaxf(v.w, 0.f);
#pragma unroll
      for (int n = 0; n < 7; ++n) {
        f32x4 w = *(const f32x4*)(W38 + (size_t)n * 4096 + c);
        ah[p][n] += v.x * w.x + v.y * w.y + v.z * w.z + v.w * w.w;
      }
    }
  }
  {
    const int c = tid * 4;
    ushort4 yv = *(const ushort4*)(Y1 + (size_t)w2 * 1024 + c);
    float4 bv = *(const float4*)(b8d + c);
    float y0 = bf2f(yv.x) + bv.x, y1 = bf2f(yv.y) + bv.y;
    float y2 = bf2f(yv.z) + bv.z, y3 = bf2f(yv.w) + bv.w;
#pragma unroll
    for (int n = 0; n < 7; ++n) {
      f32x4 w = *(const f32x4*)(W3 + (size_t)n * 1024 + c);
      ay[n] += y0 * w.x + y1 * w.y + y2 * w.z + y3 * w.w;
    }
  }

#pragma unroll
  for (int p = 0; p < 3; ++p)
#pragma unroll
    for (int n = 0; n < 7; ++n)
#pragma unroll
      for (int off = 32; off > 0; off >>= 1)
        ah[p][n] += __shfl_down(ah[p][n], off);
#pragma unroll
  for (int n = 0; n < 7; ++n)
#pragma unroll
    for (int off = 32; off > 0; off >>= 1)
      ay[n] += __shfl_down(ay[n], off);

  if (lane == 0) {
#pragma unroll
    for (int p = 0; p < 3; ++p)
#pragma unroll
      for (int n = 0; n < 7; ++n) red[wave][p * 7 + n] = ah[p][n];
#pragma unroll
    for (int n = 0; n < 7; ++n) red[wave][21 + n] = ay[n];
  }
  __syncthreads();
  if (tid < 21) {
    const int p = tid / 7, n = tid % 7;
    float v = 0.f;
#pragma unroll
    for (int w = 0; w < 4; ++w) v += red[w][tid] + red[w][21 + n];
    logits[(size_t)(w2 * 3 + p) * 7 + n] = v;
  }
}

// ---------------- out[b] = logits[cid(b)] ----------------
__global__ __launch_bounds__(256) void scatter_out(
    const int* __restrict__ items, const int* __restrict__ attr,
    const int* __restrict__ perm, const float* __restrict__ logits,
    float* __restrict__ out) {
  int b = blockIdx.x * 256 + threadIdx.x;
  int cid = ((items[b * 3] * 7 + items[b * 3 + 1]) * 7 + items[b * 3 + 2]) * 9 +
            attr[b] * 3 + perm[b];
  const float* src = logits + (size_t)cid * 7;
  float* dst = out + (size_t)b * 7;
#pragma unroll
  for (int n = 0; n < 7; ++n) dst[n] = src[n];
}

extern "C" void kernel_launch(void* const* d_in, const int* in_sizes, int n_in,
                              void* d_out, int out_size, void* d_ws, size_t ws_size,
                              hipStream_t stream) {
  const int* items = (const int*)d_in[0];
  const int* attr = (const int*)d_in[1];
  const int* perm = (const int*)d_in[2];
  const float* emb_item = (const float*)d_in[3];
  const float* W2 = (const float*)d_in[4];
  const float* W3 = (const float*)d_in[5];
  const float* emb_attr = (const float*)d_in[6];
  const float* W4 = (const float*)d_in[7];
  const float* b4 = (const float*)d_in[8];
  const float* W5 = (const float*)d_in[9];
  const float* W8u = (const float*)d_in[10];
  const float* b8u = (const float*)d_in[11];
  const float* W8d = (const float*)d_in[12];
  const float* b8d = (const float*)d_in[13];
  const float* emb_perm = (const float*)d_in[14];

  const int B = 16384, DIM = 1024, HID = 4096;

  char* ws = (char*)d_ws;
  size_t off = 0;
  auto alloc = [&](size_t bytes) {
    void* p = ws + off;
    off += (bytes + 255) & ~255ull;
    return p;
  };
  u16* W2b = (u16*)alloc((size_t)DIM * DIM * 2);
  u16* W4b = (u16*)alloc((size_t)HID * DIM * 2);
  u16* W5b = (u16*)alloc((size_t)DIM * HID * 2);
  u16* W8ub = (u16*)alloc((size_t)HID * DIM * 2);
  u16* Xe = (u16*)alloc((size_t)64 * DIM * 2);
  u16* state1b = (u16*)alloc((size_t)64 * DIM * 2);
  float* E2f = (float*)alloc((size_t)64 * DIM * 4);
  u16* state2b = (u16*)alloc((size_t)64 * DIM * 2);
  u16* X3s = (u16*)alloc((size_t)384 * DIM * 2);  // 0..342 state3; 344..346 embA
  u16* H1 = (u16*)alloc((size_t)M4 * HID * 2);
  u16* Y1 = (u16*)alloc((size_t)M4 * DIM * 2);
  float* P38 = (float*)alloc((size_t)16 * 7 * HID * 4);
  float* W38 = (float*)alloc((size_t)7 * HID * 4);
  float* logits = (float*)alloc((size_t)3087 * 7 * 4);

  float* P = (float*)(ws + off);
  const int Se = 16;  // encoder: nkt=1
  const int S4 = 2;   // FFN1-up: nkt=8,  P = 12.6 MB
  const int S5 = 4;   // FFN1-down: nkt=16, P = 18.9 MB
  const int S6 = 1;   // FFN2-up: nkt=16, P = 18.9 MB

  // prep: cvt + W38 partials + Xe
  prep<<<13632, 256, 0, stream>>>(W2, W4, W5, W8u, W2b, W4b, W5b, W8ub,
                                  W3, W8d, P38, emb_item, Xe);

  // ---- encoder, all GEMMs at M=64 ----
  gemm_sk<<<8 * Se, 256, 0, stream>>>(Xe, DIM, W2b, DIM, DIM / Se, 8, Se, P, 64 * DIM);
  r1w38<<<176, 256, 0, stream>>>(P, Se, 64 * DIM, state1b, E2f, P38, W38);
  gemm_sk<<<8 * Se, 256, 0, stream>>>(state1b, DIM, W2b, DIM, DIM / Se, 8, Se, P, 64 * DIM);
  r_expand<<<64, 256, 0, stream>>>(P, Se, 64 * DIM, 48, E2f, nullptr, state2b);
  gemm_sk<<<8 * Se, 256, 0, stream>>>(state2b, DIM, W2b, DIM, DIM / Se, 8, Se, P, 64 * DIM);
  r_expand<<<384, 256, 0, stream>>>(P, Se, 64 * DIM, 342, E2f, emb_attr, X3s);

  // ---- FFN1-up at 384 rows (stacked embA); H1 trio-expanded ----
  gemm_sk<<<6 * 32 * S4, 256, 0, stream>>>(X3s, DIM, W4b, DIM, DIM / S4, 32, S4,
                                           P, 384 * HID);
  rh1<<<1536, 256, 0, stream>>>(P, S4, 384 * HID, b4, H1);

  // ---- FFN1-down (K=4096) ----
  gemm_sk<<<18 * 8 * S5, 256, 0, stream>>>(H1, HID, W5b, HID, HID / S5, 8, S5,
                                           P, M4 * DIM);
  ry1<<<M4, 256, 0, stream>>>(P, S5, M4 * DIM, X3s, emb_attr, Y1);

  // ---- FFN2-up (no split); down-proj folded into W38 tail ----
  gemm_sk<<<18 * 32, 256, 0, stream>>>(Y1, DIM, W8ub, DIM, DIM / S6, 32, S6,
                                       P, M4 * HID);
  logits_w2<<<M4, 256, 0, stream>>>(P, b8u, emb_perm, W38, Y1, b8d, W3, logits);

  // out[b] = logits[cid(b)]
  scatter_out<<<B / 256, 256, 0, stream>>>(items, attr, perm, logits, (float*)d_out);
}